// Round 4
// baseline (602.222 us; speedup 1.0000x reference)
//
#include <hip/hip_runtime.h>
#include <hip/hip_bf16.h>

#define KS 5
#define NCH 32
#define IMH 256
#define IMW 256
#define TW 32
#define TH 8
#define HALO_W (TW + 4)
#define HALO_H (TH + 4)
#define CHUNK 4
#define NCHUNK (NCH / CHUNK)
#define TILE_ELEMS (CHUNK * HALO_H * HALO_W)
#define HW (IMH * IMW)
#define OC_CHUNK 8

__device__ __forceinline__ float sigmoidf_(float x) {
    return 1.0f / (1.0f + __expf(-x));
}

// Fully fused CIKA forward. One block = 32x8 pixel tile, one thread = 1 pixel.
// Register discipline: no per-thread array >32 floats live at once; bulky
// per-pixel intermediates (dwu_up, td) live in LDS bf16 per-thread columns.
// LDS = 6.9K (stage tile) + 16K (dwu) + 16K (td) = 38.8 KB -> 4 blocks/CU;
// grid = 1024 blocks = exactly 4/CU on 256 CUs (no tail).
__global__ __launch_bounds__(256, 4) void cika_fused(
    const float* __restrict__ lower, const float* __restrict__ upper,
    const float* __restrict__ kca_dw_w, const float* __restrict__ kca_dw_b,
    const float* __restrict__ kca_m1_w, const float* __restrict__ kca_m1_b,
    const float* __restrict__ kca_m2_w, const float* __restrict__ kca_m2_b,
    const float* __restrict__ ksa_dw_w, const float* __restrict__ ksa_dw_b,
    const float* __restrict__ ksa_m1_w, const float* __restrict__ ksa_m1_b,
    const float* __restrict__ ksa_m2_w, const float* __restrict__ ksa_m2_b,
    const float* __restrict__ low_dyn_w, const float* __restrict__ low_dyn_b,
    const float* __restrict__ low_pw_w, const float* __restrict__ low_pw_b,
    const float* __restrict__ up_dw_w, const float* __restrict__ up_dw_b,
    const float* __restrict__ up_pw_w, const float* __restrict__ up_pw_b,
    float* __restrict__ out_low, float* __restrict__ out_up)
{
    __shared__ float tile[TILE_ELEMS];              //  6912 B
    __shared__ __hip_bfloat16 dwu_lds[NCH][256];    // 16384 B (up-dw result)
    __shared__ __hip_bfloat16 td_lds[NCH][256];     // 16384 B (dynamic-dw result)

    const int tid = threadIdx.x;
    const int tx = tid & (TW - 1);
    const int ty = tid >> 5;
    const int tile_x = blockIdx.x * TW;
    const int tile_y = blockIdx.y * TH;
    const int n = blockIdx.z;
    const int x = tile_x + tx, y = tile_y + ty;
    const int pix = y * IMW + x;

    const float* lob = lower + (size_t)n * NCH * HW;
    const float* upb = upper + (size_t)n * NCH * HW;

    // ---- Phase 1: upper pass. dwu_ksa -> regs, dwu_up -> LDS bf16 ----
    float dwu_ksa[NCH];
    #pragma unroll
    for (int ck = 0; ck < NCHUNK; ++ck) {
        const int c0 = ck * CHUNK;
        __syncthreads();
        for (int idx = tid; idx < TILE_ELEMS; idx += 256) {
            int c = idx / (HALO_H * HALO_W);
            int r = idx - c * (HALO_H * HALO_W);
            int hy = r / HALO_W, hx = r - hy * HALO_W;
            int gy = tile_y + hy - 2, gx = tile_x + hx - 2;
            float v = 0.0f;
            if (gy >= 0 && gy < IMH && gx >= 0 && gx < IMW)
                v = upb[(size_t)(c0 + c) * HW + gy * IMW + gx];
            tile[idx] = v;
        }
        __syncthreads();
        #pragma unroll
        for (int cc = 0; cc < CHUNK; ++cc) {
            const int c = c0 + cc;
            float ak = ksa_dw_b[c];
            float au = up_dw_b[c];
            const float* tp = tile + cc * (HALO_H * HALO_W) + ty * HALO_W + tx;
            #pragma unroll
            for (int i = 0; i < KS; ++i)
                #pragma unroll
                for (int j = 0; j < KS; ++j) {
                    float wv = tp[i * HALO_W + j];
                    ak = fmaf(wv, ksa_dw_w[c * 25 + i * KS + j], ak);
                    au = fmaf(wv, up_dw_w[c * 25 + i * KS + j], au);
                }
            dwu_ksa[c] = fmaxf(ak, 0.0f);
            dwu_lds[c][tid] = __float2bfloat16(au);
        }
    }

    // ---- Phase 2: KSA MLP 32 -> 50(relu) -> 25(sigmoid); dwu_ksa dies ----
    float ksa[25];
    #pragma unroll
    for (int k = 0; k < 25; ++k) ksa[k] = ksa_m2_b[k];
    for (int h = 0; h < 50; ++h) {
        float hv = ksa_m1_b[h];
        #pragma unroll
        for (int c = 0; c < NCH; ++c)
            hv = fmaf(ksa_m1_w[h * NCH + c], dwu_ksa[c], hv);
        hv = fmaxf(hv, 0.0f);
        #pragma unroll
        for (int k = 0; k < 25; ++k)
            ksa[k] = fmaf(ksa_m2_w[k * 50 + h], hv, ksa[k]);
    }
    #pragma unroll
    for (int k = 0; k < 25; ++k) ksa[k] = sigmoidf_(ksa[k]);

    // ---- Phase 3: lower pass. td -> LDS bf16; kca-m1 hidden accumulated
    //      online (hv8) so no 32-wide dwl array ever exists ----
    float hv8[8];
    #pragma unroll
    for (int h = 0; h < 8; ++h) hv8[h] = kca_m1_b[h];

    #pragma unroll
    for (int ck = 0; ck < NCHUNK; ++ck) {
        const int c0 = ck * CHUNK;
        __syncthreads();
        for (int idx = tid; idx < TILE_ELEMS; idx += 256) {
            int c = idx / (HALO_H * HALO_W);
            int r = idx - c * (HALO_H * HALO_W);
            int hy = r / HALO_W, hx = r - hy * HALO_W;
            int gy = tile_y + hy - 2, gx = tile_x + hx - 2;
            float v = 0.0f;
            if (gy >= 0 && gy < IMH && gx >= 0 && gx < IMW)
                v = lob[(size_t)(c0 + c) * HW + gy * IMW + gx];
            tile[idx] = v;
        }
        __syncthreads();
        #pragma unroll
        for (int cc = 0; cc < CHUNK; ++cc) {
            const int c = c0 + cc;
            float ad = kca_dw_b[c];
            float td = low_dyn_b[c];
            const float* tp = tile + cc * (HALO_H * HALO_W) + ty * HALO_W + tx;
            #pragma unroll
            for (int i = 0; i < KS; ++i)
                #pragma unroll
                for (int j = 0; j < KS; ++j) {
                    float wv = tp[i * HALO_W + j];
                    ad = fmaf(wv, kca_dw_w[c * 25 + i * KS + j], ad);
                    td = fmaf(wv * low_dyn_w[c * 25 + i * KS + j], ksa[i * KS + j], td);
                }
            ad = fmaxf(ad, 0.0f);
            #pragma unroll
            for (int h = 0; h < 8; ++h)
                hv8[h] = fmaf(kca_m1_w[h * NCH + c], ad, hv8[h]);
            td_lds[c][tid] = __float2bfloat16(td);
        }
    }
    // ksa dead past here. td_lds/dwu_lds: same-thread column access, no barrier.

    // ---- Phase 4: out_low = low_pw @ td + b ----
    {
        float tdv[NCH];
        #pragma unroll
        for (int c = 0; c < NCH; ++c)
            tdv[c] = __bfloat162float(td_lds[c][tid]);
        float* ol = out_low + (size_t)n * NCH * HW + pix;
        #pragma unroll
        for (int oc = 0; oc < NCH / OC_CHUNK; ++oc) {
            float acc[OC_CHUNK];
            #pragma unroll
            for (int oo = 0; oo < OC_CHUNK; ++oo)
                acc[oo] = low_pw_b[oc * OC_CHUNK + oo];
            #pragma unroll
            for (int c = 0; c < NCH; ++c)
                #pragma unroll
                for (int oo = 0; oo < OC_CHUNK; ++oo)
                    acc[oo] = fmaf(low_pw_w[(oc * OC_CHUNK + oo) * NCH + c], tdv[c], acc[oo]);
            #pragma unroll
            for (int oo = 0; oo < OC_CHUNK; ++oo)
                ol[(size_t)(oc * OC_CHUNK + oo) * HW] = acc[oo];
        }
    }

    // ---- Phase 5: KCA finish: relu(hv8) -> 32 sigmoid gates ----
    float kca[NCH];
    #pragma unroll
    for (int h = 0; h < 8; ++h) hv8[h] = fmaxf(hv8[h], 0.0f);
    #pragma unroll
    for (int k = 0; k < NCH; ++k) {
        float a = kca_m2_b[k];
        #pragma unroll
        for (int h = 0; h < 8; ++h)
            a = fmaf(kca_m2_w[k * 8 + h], hv8[h], a);
        kca[k] = sigmoidf_(a);
    }

    // ---- Phase 6: up path: gate dwu by kca, pointwise ----
    {
        float t2[NCH];
        #pragma unroll
        for (int c = 0; c < NCH; ++c)
            t2[c] = __bfloat162float(dwu_lds[c][tid]) * kca[c];
        float* ou = out_up + (size_t)n * NCH * HW + pix;
        #pragma unroll
        for (int oc = 0; oc < NCH / OC_CHUNK; ++oc) {
            float acc[OC_CHUNK];
            #pragma unroll
            for (int oo = 0; oo < OC_CHUNK; ++oo)
                acc[oo] = up_pw_b[oc * OC_CHUNK + oo];
            #pragma unroll
            for (int c = 0; c < NCH; ++c)
                #pragma unroll
                for (int oo = 0; oo < OC_CHUNK; ++oo)
                    acc[oo] = fmaf(up_pw_w[(oc * OC_CHUNK + oo) * NCH + c], t2[c], acc[oo]);
            #pragma unroll
            for (int oo = 0; oo < OC_CHUNK; ++oo)
                ou[(size_t)(oc * OC_CHUNK + oo) * HW] = acc[oo];
        }
    }
}

extern "C" void kernel_launch(void* const* d_in, const int* in_sizes, int n_in,
                              void* d_out, int out_size, void* d_ws, size_t ws_size,
                              hipStream_t stream) {
    const float* lower    = (const float*)d_in[0];
    const float* upper    = (const float*)d_in[1];
    const float* kca_dw_w = (const float*)d_in[2];
    const float* kca_dw_b = (const float*)d_in[3];
    const float* kca_m1_w = (const float*)d_in[4];
    const float* kca_m1_b = (const float*)d_in[5];
    const float* kca_m2_w = (const float*)d_in[6];
    const float* kca_m2_b = (const float*)d_in[7];
    const float* ksa_dw_w = (const float*)d_in[8];
    const float* ksa_dw_b = (const float*)d_in[9];
    const float* ksa_m1_w = (const float*)d_in[10];
    const float* ksa_m1_b = (const float*)d_in[11];
    const float* ksa_m2_w = (const float*)d_in[12];
    const float* ksa_m2_b = (const float*)d_in[13];
    const float* low_dyn_w = (const float*)d_in[14];
    const float* low_dyn_b = (const float*)d_in[15];
    const float* low_pw_w  = (const float*)d_in[16];
    const float* low_pw_b  = (const float*)d_in[17];
    const float* up_dw_w   = (const float*)d_in[18];
    const float* up_dw_b   = (const float*)d_in[19];
    const float* up_pw_w   = (const float*)d_in[20];
    const float* up_pw_b   = (const float*)d_in[21];

    const int N = in_sizes[0] / (NCH * HW);
    float* out_low = (float*)d_out;
    float* out_up  = (float*)d_out + (size_t)N * NCH * HW;

    dim3 grid(IMW / TW, IMH / TH, N);
    cika_fused<<<grid, dim3(256), 0, stream>>>(
        lower, upper,
        kca_dw_w, kca_dw_b, kca_m1_w, kca_m1_b, kca_m2_w, kca_m2_b,
        ksa_dw_w, ksa_dw_b, ksa_m1_w, ksa_m1_b, ksa_m2_w, ksa_m2_b,
        low_dyn_w, low_dyn_b, low_pw_w, low_pw_b,
        up_dw_w, up_dw_b, up_pw_w, up_pw_b,
        out_low, out_up);
}